// Round 1
// baseline (801.151 us; speedup 1.0000x reference)
//
#include <hip/hip_runtime.h>
#include <hip/hip_bf16.h>

#define D 64
#define TJ 1024

// ---------------- Kernel A: per-row squared norms + partial sum of sq (f64) ----------------
__global__ __launch_bounds__(256) void k_sq(const float* __restrict__ x, const float* __restrict__ y,
                                            int nx, float* __restrict__ sq, double* __restrict__ Tpart) {
    int i = blockIdx.x * 256 + threadIdx.x;
    const float* rowp = (i < nx) ? (x + (size_t)i * D) : (y + (size_t)(i - nx) * D);
    const float4* r4 = (const float4*)rowp;
    float s = 0.f;
#pragma unroll
    for (int k = 0; k < 16; ++k) {
        float4 v = r4[k];
        s += v.x * v.x + v.y * v.y + v.z * v.z + v.w * v.w;
    }
    sq[i] = s;

    __shared__ double red[256];
    red[threadIdx.x] = (double)s;
    __syncthreads();
    for (int off = 128; off > 0; off >>= 1) {
        if (threadIdx.x < off) red[threadIdx.x] += red[threadIdx.x + off];
        __syncthreads();
    }
    if (threadIdx.x == 0) Tpart[blockIdx.x] = red[0];
}

// ---------------- Kernel A2: partial column sums (for ||sum z||^2) ----------------
__global__ __launch_bounds__(256) void k_colsum(const float* __restrict__ x, const float* __restrict__ y,
                                                int nx, float* __restrict__ Spart) {
    int k = threadIdx.x & (D - 1);
    int g = threadIdx.x >> 6;           // 4 row-groups of 64 rows
    int row0 = blockIdx.x * 256 + g * 64;
    float s = 0.f;
    for (int r = 0; r < 64; ++r) {
        int i = row0 + r;
        const float* rowp = (i < nx) ? (x + (size_t)i * D) : (y + (size_t)(i - nx) * D);
        s += rowp[k];                   // lanes k=0..63 read consecutive addresses: coalesced
    }
    __shared__ float red[256];
    red[threadIdx.x] = s;
    __syncthreads();
    if (g == 0) Spart[blockIdx.x * D + k] = red[k] + red[64 + k] + red[128 + k] + red[192 + k];
}

// ---------------- Kernel B: finalize bandwidth, store 1/bw ----------------
__global__ __launch_bounds__(64) void k_bw(const double* __restrict__ Tpart, const float* __restrict__ Spart,
                                           int nblocks, int N, float* __restrict__ invbw) {
    int t = threadIdx.x;
    // column sums over all block-partials (coalesced across t)
    double Sk = 0.0;
    for (int b = 0; b < nblocks; ++b) Sk += (double)Spart[b * D + t];
    double v = Sk * Sk;
    double Tp = 0.0;
    for (int b = t; b < nblocks; b += 64) Tp += Tpart[b];

    __shared__ double red[128];
    red[t] = v;
    red[64 + t] = Tp;
    __syncthreads();
    for (int off = 32; off > 0; off >>= 1) {
        if (t < off) {
            red[t] += red[t + off];
            red[64 + t] += red[64 + t + off];
        }
        __syncthreads();
    }
    if (t == 0) {
        double S2 = red[0];
        double T = red[64];
        double sumd2 = 2.0 * (double)N * T - 2.0 * S2;   // clamp correction negligible (diag ~ 0)
        double bw = sumd2 / ((double)N * (double)N - (double)N);
        invbw[0] = (float)(1.0 / bw);
    }
}

// ---------------- Kernel C: main pairwise pass ----------------
// grid = (N/256 i-blocks) x (N/TJ j-chunks); each lane owns row i in VGPRs,
// j-row address is wave-uniform -> scalar loads; K = E^4+E^2+E+sqrt(E)+sqrt(sqrt(E)).
__global__ __launch_bounds__(256) void k_mmd(const float* __restrict__ x, const float* __restrict__ y,
                                             const float* __restrict__ sq, const float* __restrict__ invbw_p,
                                             int nx, int nib, double* __restrict__ partial) {
    int bid = blockIdx.x;
    int ib = bid % nib;        // i-block
    int c  = bid / nib;        // j-chunk
    int i  = ib * 256 + threadIdx.x;
    int j0 = c * TJ;

    const float inv_bw = invbw_p[0];

    float r[D];
    {
        const float* rowp = (i < nx) ? (x + (size_t)i * D) : (y + (size_t)(i - nx) * D);
        const float4* r4 = (const float4*)rowp;
#pragma unroll
        for (int k = 0; k < 16; ++k) ((float4*)r)[k] = r4[k];
    }
    float sqi = sq[i];

    // whole j-chunk is entirely within x or y (TJ divides nx)
    const float* zsrc = (j0 < nx) ? (x + (size_t)j0 * D) : (y + (size_t)(j0 - nx) * D);

    double acc = 0.0;
    for (int j = 0; j < TJ; ++j) {
        const float4* s4 = (const float4*)(zsrc + (size_t)j * D);
        float d0 = 0.f, d1 = 0.f, d2 = 0.f, d3 = 0.f;
#pragma unroll
        for (int kk = 0; kk < 16; ++kk) {
            float4 sv = s4[kk];
            d0 = fmaf(r[4 * kk + 0], sv.x, d0);
            d1 = fmaf(r[4 * kk + 1], sv.y, d1);
            d2 = fmaf(r[4 * kk + 2], sv.z, d2);
            d3 = fmaf(r[4 * kk + 3], sv.w, d3);
        }
        float dot = (d0 + d1) + (d2 + d3);
        float sqj = sq[j0 + j];
        float dd = fmaxf(sqi + sqj - 2.0f * dot, 0.0f);
        float tt = dd * inv_bw;
        float E  = __expf(-tt);
        float E2 = E * E;
        float E4 = E2 * E2;
        float s1 = sqrtf(E);
        float s2 = sqrtf(s1);
        acc += (double)(((E4 + E2) + E) + (s1 + s2));
    }

    __shared__ double red[256];
    red[threadIdx.x] = acc;
    __syncthreads();
    for (int off = 128; off > 0; off >>= 1) {
        if (threadIdx.x < off) red[threadIdx.x] += red[threadIdx.x + off];
        __syncthreads();
    }
    if (threadIdx.x == 0) partial[bid] = red[0];
}

// ---------------- Kernel D: classify block partials into XX/XY/YY, finalize ----------------
__global__ __launch_bounds__(256) void k_final(const double* __restrict__ partial, int nib, int nb,
                                               int nx, int ny, float* __restrict__ out) {
    int t = threadIdx.x;
    double sXX = 0.0, sXY = 0.0, sYY = 0.0;
    for (int p = t; p < nb; p += 256) {
        int ib = p % nib;
        int c  = p / nib;
        bool iX = (ib * 256) < nx;
        bool jX = (c * TJ) < nx;
        double v = partial[p];
        if (iX && jX) sXX += v;
        else if (iX != jX) sXY += v;   // both (x,y) and (y,x) halves land here
        else sYY += v;
    }
    __shared__ double r0[256], r1[256], r2[256];
    r0[t] = sXX; r1[t] = sXY; r2[t] = sYY;
    __syncthreads();
    for (int off = 128; off > 0; off >>= 1) {
        if (t < off) {
            r0[t] += r0[t + off];
            r1[t] += r1[t + off];
            r2[t] += r2[t + off];
        }
        __syncthreads();
    }
    if (t == 0) {
        double XX = r0[0] / ((double)nx * (double)nx);
        double XY = r1[0] / (2.0 * (double)nx * (double)ny); // two symmetric halves summed
        double YY = r2[0] / ((double)ny * (double)ny);
        out[0] = (float)(XX - 2.0 * XY + YY);
    }
}

extern "C" void kernel_launch(void* const* d_in, const int* in_sizes, int n_in,
                              void* d_out, int out_size, void* d_ws, size_t ws_size,
                              hipStream_t stream) {
    const float* x = (const float*)d_in[0];
    const float* y = (const float*)d_in[1];
    float* out = (float*)d_out;

    int nx = in_sizes[0] / D;   // 8192
    int ny = in_sizes[1] / D;   // 8192
    int N  = nx + ny;           // 16384
    int nib = N / 256;          // 64 i-blocks
    int jchunks = N / TJ;       // 16 j-chunks
    int nb = nib * jchunks;     // 1024 pair-blocks

    // workspace layout (all written before read; no zero-init needed)
    char* w = (char*)d_ws;
    float*  sq     = (float*) (w + 0);            // N floats        (65536 B)
    double* Tpart  = (double*)(w + 65536);        // nib doubles     (512 B)
    float*  Spart  = (float*) (w + 66048);        // nib*64 floats   (16384 B)
    float*  invbw  = (float*) (w + 82432);        // 1 float
    double* partial= (double*)(w + 82944);        // nb doubles      (8192 B)

    k_sq    <<<nib, 256, 0, stream>>>(x, y, nx, sq, Tpart);
    k_colsum<<<nib, 256, 0, stream>>>(x, y, nx, Spart);
    k_bw    <<<1,   64,  0, stream>>>(Tpart, Spart, nib, N, invbw);
    k_mmd   <<<nb,  256, 0, stream>>>(x, y, sq, invbw, nx, nib, partial);
    k_final <<<1,   256, 0, stream>>>(partial, nib, nb, nx, ny, out);
}

// Round 4
// 223.812 us; speedup vs baseline: 3.5796x; 3.5796x over previous
//
#include <hip/hip_runtime.h>
#include <hip/hip_bf16.h>

#define D 64

typedef __attribute__((ext_vector_type(8))) _Float16 half8;
typedef __attribute__((ext_vector_type(4))) float floatx4;

// ---------------- Kernel A: per-row squared norms (f32 exact) + partial sum (f64) ----------------
__global__ __launch_bounds__(256) void k_sq(const float* __restrict__ x, const float* __restrict__ y,
                                            int nx, float* __restrict__ sq, double* __restrict__ Tpart) {
    int i = blockIdx.x * 256 + threadIdx.x;
    const float* rowp = (i < nx) ? (x + (size_t)i * D) : (y + (size_t)(i - nx) * D);
    const float4* r4 = (const float4*)rowp;
    float s = 0.f;
#pragma unroll
    for (int k = 0; k < 16; ++k) {
        float4 v = r4[k];
        s += v.x * v.x + v.y * v.y + v.z * v.z + v.w * v.w;
    }
    sq[i] = s;

    __shared__ double red[256];
    red[threadIdx.x] = (double)s;
    __syncthreads();
    for (int off = 128; off > 0; off >>= 1) {
        if (threadIdx.x < off) red[threadIdx.x] += red[threadIdx.x + off];
        __syncthreads();
    }
    if (threadIdx.x == 0) Tpart[blockIdx.x] = red[0];
}

// ---------------- Kernel A2: partial column sums (for ||sum z||^2) ----------------
__global__ __launch_bounds__(256) void k_colsum(const float* __restrict__ x, const float* __restrict__ y,
                                                int nx, float* __restrict__ Spart) {
    int k = threadIdx.x & (D - 1);
    int g = threadIdx.x >> 6;
    int row0 = blockIdx.x * 256 + g * 64;
    float s = 0.f;
    for (int r = 0; r < 64; ++r) {
        int i = row0 + r;
        const float* rowp = (i < nx) ? (x + (size_t)i * D) : (y + (size_t)(i - nx) * D);
        s += rowp[k];
    }
    __shared__ float red[256];
    red[threadIdx.x] = s;
    __syncthreads();
    if (g == 0) Spart[blockIdx.x * D + k] = red[k] + red[64 + k] + red[128 + k] + red[192 + k];
}

// ---------------- Kernel B: finalize bandwidth; store cexp = log2(e)/bw ----------------
__global__ __launch_bounds__(64) void k_bw(const double* __restrict__ Tpart, const float* __restrict__ Spart,
                                           int nblocks, int N, float* __restrict__ cexp_p) {
    int t = threadIdx.x;
    double Sk = 0.0;
    for (int b = 0; b < nblocks; ++b) Sk += (double)Spart[b * D + t];
    double v = Sk * Sk;
    double Tp = 0.0;
    for (int b = t; b < nblocks; b += 64) Tp += Tpart[b];

    __shared__ double red[128];
    red[t] = v;
    red[64 + t] = Tp;
    __syncthreads();
    for (int off = 32; off > 0; off >>= 1) {
        if (t < off) {
            red[t] += red[t + off];
            red[64 + t] += red[64 + t + off];
        }
        __syncthreads();
    }
    if (t == 0) {
        double S2 = red[0];
        double T = red[64];
        double sumd2 = 2.0 * (double)N * T - 2.0 * S2;
        double bw = sumd2 / ((double)N * (double)N - (double)N);
        cexp_p[0] = (float)(1.4426950408889634 / bw);   // log2(e)/bw
    }
}

// ---------------- Kernel A3: convert z -> fp16 (row-major [N][64]) ----------------
__global__ __launch_bounds__(256) void k_convert(const float* __restrict__ x, const float* __restrict__ y,
                                                 int nx, _Float16* __restrict__ zh) {
    int t = blockIdx.x * 256 + threadIdx.x;      // each thread converts 8 elements
    size_t e = (size_t)t * 8;
    size_t row = e >> 6;
    const float* src = (row < (size_t)nx) ? (x + e) : (y + (e - (size_t)nx * D));
    float4 v0 = ((const float4*)src)[0];
    float4 v1 = ((const float4*)src)[1];
    half8 h;
    h[0] = (_Float16)v0.x; h[1] = (_Float16)v0.y; h[2] = (_Float16)v0.z; h[3] = (_Float16)v0.w;
    h[4] = (_Float16)v1.x; h[5] = (_Float16)v1.y; h[6] = (_Float16)v1.z; h[7] = (_Float16)v1.w;
    *(half8*)(zh + e) = h;
}

// ---------------- Kernel A4: nsqc[i] = -sq[i] * cexp ----------------
__global__ __launch_bounds__(256) void k_scale(const float* __restrict__ sq, const float* __restrict__ cexp_p,
                                               float* __restrict__ nsqc) {
    int i = blockIdx.x * 256 + threadIdx.x;
    nsqc[i] = -sq[i] * cexp_p[0];
}

// ---------------- Kernel C: main pairwise pass via MFMA ----------------
// Per wave: 32 i-rows (two 16-row A tiles, K=64 in 4 half8 frags), loop over 16-j tiles
// of a 2048-wide j chunk. C layout (m89): col = lane&15, row = (lane>>4)*4 + reg.
// u = (2*dot - sqi - sqj) * log2e/bw  (<=0 after clamp), K = E^4+E^2+E+E^.5+E^.25, E=2^u.
__global__ __launch_bounds__(256, 4) void k_mmd(const _Float16* __restrict__ zh,
                                                const float* __restrict__ nsqc,
                                                const float* __restrict__ cexp_p,
                                                int nib, int jchunk, double* __restrict__ partial) {
    int bid = blockIdx.x;
    int ib = bid % nib;          // 128-row i block
    int c  = bid / nib;          // jchunk-wide j chunk
    int lane = threadIdx.x & 63;
    int wid  = threadIdx.x >> 6;
    int i0 = ib * 128 + wid * 32;
    int j0 = c * jchunk;

    float c2p = 2.0f * cexp_p[0];

    int lrow = lane & 15;
    int kb = (lane >> 4) * 8;

    const _Float16* ar0 = zh + (size_t)(i0 + lrow) * D + kb;
    const _Float16* ar1 = zh + (size_t)(i0 + 16 + lrow) * D + kb;
    half8 a00 = *(const half8*)(ar0);
    half8 a01 = *(const half8*)(ar0 + 32);
    half8 a10 = *(const half8*)(ar1);
    half8 a11 = *(const half8*)(ar1 + 32);

    int irh = (lane >> 4) * 4;
    float nai0[4], nai1[4];
#pragma unroll
    for (int r = 0; r < 4; ++r) {
        nai0[r] = nsqc[i0 + irh + r];
        nai1[r] = nsqc[i0 + 16 + irh + r];
    }

    const _Float16* bptr = zh + (size_t)(j0 + lrow) * D + kb;
    const float* nsqj = nsqc + j0 + lrow;
    int niter = jchunk / 16;

    double acc = 0.0;
    for (int jt = 0; jt < niter; ++jt) {
        half8 b0 = *(const half8*)(bptr);
        half8 b1 = *(const half8*)(bptr + 32);
        float nbj = *nsqj;
        floatx4 d0 = {0.f, 0.f, 0.f, 0.f};
        floatx4 d1 = {0.f, 0.f, 0.f, 0.f};
        d0 = __builtin_amdgcn_mfma_f32_16x16x32_f16(a00, b0, d0, 0, 0, 0);
        d0 = __builtin_amdgcn_mfma_f32_16x16x32_f16(a01, b1, d0, 0, 0, 0);
        d1 = __builtin_amdgcn_mfma_f32_16x16x32_f16(a10, b0, d1, 0, 0, 0);
        d1 = __builtin_amdgcn_mfma_f32_16x16x32_f16(a11, b1, d1, 0, 0, 0);

        float part = 0.f;
#pragma unroll
        for (int r = 0; r < 4; ++r) {
            float u0 = fminf(fmaf(d0[r], c2p, nai0[r] + nbj), 0.f);
            float u1 = fminf(fmaf(d1[r], c2p, nai1[r] + nbj), 0.f);
            float E0 = __builtin_amdgcn_exp2f(u0);
            float E1 = __builtin_amdgcn_exp2f(u1);
            float E02 = E0 * E0, E04 = E02 * E02;
            float s01 = __builtin_amdgcn_sqrtf(E0), s02 = __builtin_amdgcn_sqrtf(s01);
            float E12 = E1 * E1, E14 = E12 * E12;
            float s11 = __builtin_amdgcn_sqrtf(E1), s12 = __builtin_amdgcn_sqrtf(s11);
            part += ((E04 + E02) + (E0 + (s01 + s02))) + ((E14 + E12) + (E1 + (s11 + s12)));
        }
        acc += (double)part;

        bptr += (size_t)16 * D;
        nsqj += 16;
    }

    __shared__ double red[256];
    red[threadIdx.x] = acc;
    __syncthreads();
    for (int off = 128; off > 0; off >>= 1) {
        if (threadIdx.x < off) red[threadIdx.x] += red[threadIdx.x + off];
        __syncthreads();
    }
    if (threadIdx.x == 0) partial[bid] = red[0];
}

// ---------------- Kernel D: classify block partials into XX/XY/YY, finalize ----------------
__global__ __launch_bounds__(256) void k_final(const double* __restrict__ partial, int nib, int nb,
                                               int jchunk, int nx, int ny, float* __restrict__ out) {
    int t = threadIdx.x;
    double sXX = 0.0, sXY = 0.0, sYY = 0.0;
    for (int p = t; p < nb; p += 256) {
        int ib = p % nib;
        int c  = p / nib;
        bool iX = (ib * 128) < nx;
        bool jX = (c * jchunk) < nx;
        double v = partial[p];
        if (iX && jX) sXX += v;
        else if (iX != jX) sXY += v;
        else sYY += v;
    }
    __shared__ double r0[256], r1[256], r2[256];
    r0[t] = sXX; r1[t] = sXY; r2[t] = sYY;
    __syncthreads();
    for (int off = 128; off > 0; off >>= 1) {
        if (t < off) {
            r0[t] += r0[t + off];
            r1[t] += r1[t + off];
            r2[t] += r2[t + off];
        }
        __syncthreads();
    }
    if (t == 0) {
        double XX = r0[0] / ((double)nx * (double)nx);
        double XY = r1[0] / (2.0 * (double)nx * (double)ny);
        double YY = r2[0] / ((double)ny * (double)ny);
        out[0] = (float)(XX - 2.0 * XY + YY);
    }
}

extern "C" void kernel_launch(void* const* d_in, const int* in_sizes, int n_in,
                              void* d_out, int out_size, void* d_ws, size_t ws_size,
                              hipStream_t stream) {
    const float* x = (const float*)d_in[0];
    const float* y = (const float*)d_in[1];
    float* out = (float*)d_out;

    int nx = in_sizes[0] / D;    // 8192
    int ny = in_sizes[1] / D;    // 8192
    int N  = nx + ny;            // 16384

    int nsq_blocks = N / 256;    // 64  (k_sq / k_colsum / k_scale grids)
    int nib    = N / 128;        // 128 i-blocks for k_mmd
    int jchunk = 2048;
    int nchunk = N / jchunk;     // 8
    int nb     = nib * nchunk;   // 1024 pair-blocks

    // workspace layout (all buffers fully written before read every launch)
    char* w = (char*)d_ws;
    double* Tpart   = (double*)(w + 0);        // 64 * 8        = 512 B
    double* partial = (double*)(w + 512);      // 1024 * 8      = 8192 B   -> 8704
    float*  Spart   = (float*) (w + 8704);     // 64*64*4       = 16384 B  -> 25088
    float*  sq      = (float*) (w + 25088);    // N*4           = 65536 B  -> 90624
    float*  nsqc    = (float*) (w + 90624);    // N*4           = 65536 B  -> 156160
    float*  cexp    = (float*) (w + 156160);   // 4 B (pad to 64)          -> 156224
    _Float16* zh    = (_Float16*)(w + 156224); // N*64*2        = 2 MiB

    k_sq     <<<nsq_blocks, 256, 0, stream>>>(x, y, nx, sq, Tpart);
    k_colsum <<<nsq_blocks, 256, 0, stream>>>(x, y, nx, Spart);
    k_bw     <<<1, 64, 0, stream>>>(Tpart, Spart, nsq_blocks, N, cexp);
    k_convert<<<(N * D / 8) / 256, 256, 0, stream>>>(x, y, nx, zh);
    k_scale  <<<nsq_blocks, 256, 0, stream>>>(sq, cexp, nsqc);
    k_mmd    <<<nb, 256, 0, stream>>>(zh, nsqc, cexp, nib, jchunk, partial);
    k_final  <<<1, 256, 0, stream>>>(partial, nib, nb, jchunk, nx, ny, out);
}

// Round 5
// 188.274 us; speedup vs baseline: 4.2552x; 1.1888x over previous
//
#include <hip/hip_runtime.h>
#include <hip/hip_bf16.h>

#define D 64

typedef __attribute__((ext_vector_type(8))) _Float16 half8;
typedef __attribute__((ext_vector_type(4))) float floatx4;

// ---- k_pre: fp16 convert + per-row sq + block partial sum(z^2) ----
__global__ __launch_bounds__(256) void k_pre(const float* __restrict__ x, const float* __restrict__ y,
                                             int nx, _Float16* __restrict__ zh,
                                             float* __restrict__ sq, double* __restrict__ Tpart) {
    int t = blockIdx.x * 256 + threadIdx.x;     // 8 elements per thread
    size_t e = (size_t)t * 8;
    int row = (int)(e >> 6);
    const float* src = (row < nx) ? (x + e) : (y + (e - (size_t)nx * D));
    float4 v0 = ((const float4*)src)[0];
    float4 v1 = ((const float4*)src)[1];
    half8 h;
    h[0]=(_Float16)v0.x; h[1]=(_Float16)v0.y; h[2]=(_Float16)v0.z; h[3]=(_Float16)v0.w;
    h[4]=(_Float16)v1.x; h[5]=(_Float16)v1.y; h[6]=(_Float16)v1.z; h[7]=(_Float16)v1.w;
    *(half8*)(zh + e) = h;
    float p = v0.x*v0.x + v0.y*v0.y + v0.z*v0.z + v0.w*v0.w
            + v1.x*v1.x + v1.y*v1.y + v1.z*v1.z + v1.w*v1.w;
    // row-sum across the 8 consecutive lanes sharing this row
    float s = p;
    s += __shfl_xor(s, 1);
    s += __shfl_xor(s, 2);
    s += __shfl_xor(s, 4);
    if ((threadIdx.x & 7) == 0) sq[row] = s;
    __shared__ double red[256];
    red[threadIdx.x] = (double)p;
    __syncthreads();
    for (int off = 128; off > 0; off >>= 1) {
        if (threadIdx.x < off) red[threadIdx.x] += red[threadIdx.x + off];
        __syncthreads();
    }
    if (threadIdx.x == 0) Tpart[blockIdx.x] = red[0];
}

// ---- k_colsum: partial column sums (for ||sum z||^2) ----
__global__ __launch_bounds__(256) void k_colsum(const float* __restrict__ x, const float* __restrict__ y,
                                                int nx, float* __restrict__ Spart) {
    int k = threadIdx.x & (D - 1);
    int g = threadIdx.x >> 6;
    int row0 = blockIdx.x * 256 + g * 64;
    float s = 0.f;
    for (int r = 0; r < 64; ++r) {
        int i = row0 + r;
        const float* rowp = (i < nx) ? (x + (size_t)i * D) : (y + (size_t)(i - nx) * D);
        s += rowp[k];
    }
    __shared__ float red[256];
    red[threadIdx.x] = s;
    __syncthreads();
    if (g == 0) Spart[blockIdx.x * D + k] = red[k] + red[64 + k] + red[128 + k] + red[192 + k];
}

// ---- k_bw2: finalize bandwidth (cq = log2e/(4 bw)) + nsqq[i] = -sq[i]*cq ----
__global__ __launch_bounds__(256) void k_bw2(const double* __restrict__ Tpart, int ntp,
                                             const float* __restrict__ Spart, int nsp,
                                             int N, const float* __restrict__ sq,
                                             float* __restrict__ nsqq, float* __restrict__ cq_p) {
    int t = threadIdx.x;
    __shared__ double red[256];
    __shared__ float cqs;
    double v = 0.0;
    if (t < 64) {
        double Sk = 0.0;
        for (int b = 0; b < nsp; ++b) Sk += (double)Spart[b * D + t];
        v = Sk * Sk;
    }
    double Tp = 0.0;
    for (int b = t; b < ntp; b += 256) Tp += Tpart[b];

    red[t] = v;
    __syncthreads();
    for (int off = 128; off > 0; off >>= 1) {
        if (t < off) red[t] += red[t + off];
        __syncthreads();
    }
    double S2 = red[0];
    __syncthreads();
    red[t] = Tp;
    __syncthreads();
    for (int off = 128; off > 0; off >>= 1) {
        if (t < off) red[t] += red[t + off];
        __syncthreads();
    }
    if (t == 0) {
        double T = red[0];
        double sumd2 = 2.0 * (double)N * T - 2.0 * S2;
        double bw = sumd2 / ((double)N * (double)N - (double)N);
        float cq = (float)(1.4426950408889634 / (4.0 * bw));
        cq_p[0] = cq;
        cqs = cq;
    }
    __syncthreads();
    float cq = cqs;
    for (int it = 0; it < N / 256; ++it) {
        int i = it * 256 + t;
        nsqq[i] = -sq[i] * cq;
    }
}

// ---- k_mmd: lower-triangle 128x128 tiles via MFMA ----
// u4 = (2*dot - sqi - sqj)*log2e/(4bw) (clamped <=0); Eq=2^u4;
// K = Eq + Eq^2 + Eq^4 + Eq^8 + Eq^16  (= E^.25+E^.5+E+E^2+E^4, E=e^{-d2/bw}).
__global__ __launch_bounds__(256, 6) void k_mmd(const _Float16* __restrict__ zh,
                                                const float* __restrict__ nsqq,
                                                const float* __restrict__ cq_p,
                                                double* __restrict__ partial) {
    int bid = blockIdx.x;
    int ib = (int)((sqrtf(8.0f * (float)bid + 1.0f) - 1.0f) * 0.5f);
    while ((ib + 1) * (ib + 2) / 2 <= bid) ++ib;
    while (ib * (ib + 1) / 2 > bid) --ib;
    int jb = bid - ib * (ib + 1) / 2;           // jb <= ib

    int lane = threadIdx.x & 63;
    int wid  = threadIdx.x >> 6;
    int i0 = ib * 128 + wid * 32;
    int j0 = jb * 128;

    float c2q = 2.0f * cq_p[0];

    int lrow = lane & 15;
    int kb = (lane >> 4) * 8;

    const _Float16* ar0 = zh + (size_t)(i0 + lrow) * D + kb;
    half8 a00 = *(const half8*)(ar0);
    half8 a01 = *(const half8*)(ar0 + 32);
    half8 a10 = *(const half8*)(ar0 + 16 * D);
    half8 a11 = *(const half8*)(ar0 + 16 * D + 32);

    int irh = (lane >> 4) * 4;
    float nai0[4], nai1[4];
#pragma unroll
    for (int r = 0; r < 4; ++r) {
        nai0[r] = nsqq[i0 + irh + r];
        nai1[r] = nsqq[i0 + 16 + irh + r];
    }

    const _Float16* bptr = zh + (size_t)(j0 + lrow) * D + kb;
    const float* nsqj = nsqq + j0 + lrow;

    double acc = 0.0;
#pragma unroll 2
    for (int jt = 0; jt < 8; ++jt) {
        half8 b0 = *(const half8*)(bptr);
        half8 b1 = *(const half8*)(bptr + 32);
        float nbj = nsqj[0];
        floatx4 d0 = {0.f, 0.f, 0.f, 0.f};
        floatx4 d1 = {0.f, 0.f, 0.f, 0.f};
        d0 = __builtin_amdgcn_mfma_f32_16x16x32_f16(a00, b0, d0, 0, 0, 0);
        d0 = __builtin_amdgcn_mfma_f32_16x16x32_f16(a01, b1, d0, 0, 0, 0);
        d1 = __builtin_amdgcn_mfma_f32_16x16x32_f16(a10, b0, d1, 0, 0, 0);
        d1 = __builtin_amdgcn_mfma_f32_16x16x32_f16(a11, b1, d1, 0, 0, 0);

        float part = 0.f;
#pragma unroll
        for (int r = 0; r < 4; ++r) {
            float u0 = fminf(fmaf(d0[r], c2q, nai0[r] + nbj), 0.f);
            float u1 = fminf(fmaf(d1[r], c2q, nai1[r] + nbj), 0.f);
            float q0 = __builtin_amdgcn_exp2f(u0);
            float q1 = __builtin_amdgcn_exp2f(u1);
            float m01 = q0 * q0,   m11 = q1 * q1;     // Eq^2
            float m02 = m01 * m01, m12 = m11 * m11;   // Eq^4
            float m03 = m02 * m02, m13 = m12 * m12;   // Eq^8
            float s0 = (q0 + m01) + (m02 + m03);
            float s1 = (q1 + m11) + (m12 + m13);
            part += fmaf(m03, m03, s0) + fmaf(m13, m13, s1);  // + Eq^16
        }
        acc += (double)part;

        bptr += (size_t)16 * D;
        nsqj += 16;
    }

    __shared__ double red[256];
    red[threadIdx.x] = acc;
    __syncthreads();
    for (int off = 128; off > 0; off >>= 1) {
        if (threadIdx.x < off) red[threadIdx.x] += red[threadIdx.x + off];
        __syncthreads();
    }
    if (threadIdx.x == 0) partial[bid] = red[0];
}

// ---- k_final: weight (diag x1, off-diag x2), classify, finalize ----
__global__ __launch_bounds__(256) void k_final(const double* __restrict__ partial, int nb, int nxTile,
                                               int nx, int ny, float* __restrict__ out) {
    int t = threadIdx.x;
    double sXX = 0.0, sXY = 0.0, sYY = 0.0;
    for (int p = t; p < nb; p += 256) {
        int ib = (int)((sqrtf(8.0f * (float)p + 1.0f) - 1.0f) * 0.5f);
        while ((ib + 1) * (ib + 2) / 2 <= p) ++ib;
        while (ib * (ib + 1) / 2 > p) --ib;
        int jb = p - ib * (ib + 1) / 2;
        double v = (ib == jb ? 1.0 : 2.0) * partial[p];
        bool iX = ib < nxTile;
        bool jX = jb < nxTile;
        if (iX && jX) sXX += v;
        else if (iX != jX) sXY += v;
        else sYY += v;
    }
    __shared__ double r0[256], r1[256], r2[256];
    r0[t] = sXX; r1[t] = sXY; r2[t] = sYY;
    __syncthreads();
    for (int off = 128; off > 0; off >>= 1) {
        if (t < off) {
            r0[t] += r0[t + off];
            r1[t] += r1[t + off];
            r2[t] += r2[t + off];
        }
        __syncthreads();
    }
    if (t == 0) {
        double XX = r0[0] / ((double)nx * (double)nx);
        double XY = r1[0] / (2.0 * (double)nx * (double)ny);  // doubled mixed tiles = both halves
        double YY = r2[0] / ((double)ny * (double)ny);
        out[0] = (float)(XX - 2.0 * XY + YY);
    }
}

extern "C" void kernel_launch(void* const* d_in, const int* in_sizes, int n_in,
                              void* d_out, int out_size, void* d_ws, size_t ws_size,
                              hipStream_t stream) {
    const float* x = (const float*)d_in[0];
    const float* y = (const float*)d_in[1];
    float* out = (float*)d_out;

    int nx = in_sizes[0] / D;     // 8192
    int ny = in_sizes[1] / D;     // 8192
    int N  = nx + ny;             // 16384

    int pre_blocks = (N * D / 8) / 256;   // 512
    int cs_blocks  = N / 256;             // 64
    int nT = N / 128;                     // 128 tiles per side
    int nxTile = nx / 128;                // 64
    int nb = nT * (nT + 1) / 2;           // 8256 lower-triangle tile-blocks

    // workspace layout (every buffer fully written before read, every launch)
    char* w = (char*)d_ws;
    double* Tpart   = (double*)(w + 0);        // 512*8   = 4096          -> 4096
    double* partial = (double*)(w + 4096);     // 8256*8  = 66048         -> 70144
    float*  Spart   = (float*) (w + 70144);    // 64*64*4 = 16384         -> 86528
    float*  sq      = (float*) (w + 86528);    // N*4     = 65536         -> 152064
    float*  nsqq    = (float*) (w + 152064);   // N*4     = 65536         -> 217600
    float*  cq      = (float*) (w + 217600);   // 64 B pad                -> 217664
    _Float16* zh    = (_Float16*)(w + 217664); // N*64*2  = 2 MiB

    k_pre    <<<pre_blocks, 256, 0, stream>>>(x, y, nx, zh, sq, Tpart);
    k_colsum <<<cs_blocks,  256, 0, stream>>>(x, y, nx, Spart);
    k_bw2    <<<1, 256, 0, stream>>>(Tpart, pre_blocks, Spart, cs_blocks, N, sq, nsqq, cq);
    k_mmd    <<<nb, 256, 0, stream>>>(zh, nsqq, cq, partial);
    k_final  <<<1, 256, 0, stream>>>(partial, nb, nxTile, nx, ny, out);
}

// Round 6
// 184.434 us; speedup vs baseline: 4.3438x; 1.0208x over previous
//
#include <hip/hip_runtime.h>
#include <hip/hip_bf16.h>

#define D 64

typedef __attribute__((ext_vector_type(8))) _Float16 half8;
typedef __attribute__((ext_vector_type(4))) float floatx4;

// ---- k_pre: fp16 convert + per-row sq + block partial sum(z^2) + block column sums ----
__global__ __launch_bounds__(256) void k_pre(const float* __restrict__ x, const float* __restrict__ y,
                                             int nx, _Float16* __restrict__ zh,
                                             float* __restrict__ sq, double* __restrict__ Tpart,
                                             float* __restrict__ Spart) {
    int tid = threadIdx.x;
    int t = blockIdx.x * 256 + tid;             // 8 elements per thread; block = 32 rows
    size_t e = (size_t)t * 8;
    int row = (int)(e >> 6);
    const float* src = (row < nx) ? (x + e) : (y + (e - (size_t)nx * D));
    float4 v0 = ((const float4*)src)[0];
    float4 v1 = ((const float4*)src)[1];
    half8 h;
    h[0]=(_Float16)v0.x; h[1]=(_Float16)v0.y; h[2]=(_Float16)v0.z; h[3]=(_Float16)v0.w;
    h[4]=(_Float16)v1.x; h[5]=(_Float16)v1.y; h[6]=(_Float16)v1.z; h[7]=(_Float16)v1.w;
    *(half8*)(zh + e) = h;
    float p = v0.x*v0.x + v0.y*v0.y + v0.z*v0.z + v0.w*v0.w
            + v1.x*v1.x + v1.y*v1.y + v1.z*v1.z + v1.w*v1.w;
    // row-sum across the 8 consecutive lanes sharing this row
    float s = p;
    s += __shfl_xor(s, 1);
    s += __shfl_xor(s, 2);
    s += __shfl_xor(s, 4);
    if ((tid & 7) == 0) sq[row] = s;

    // stage this thread's 8 column values for the block column-sum
    __shared__ float colbuf[32][64];
    int rib = tid >> 3, cg = tid & 7;
    *(float4*)&colbuf[rib][cg * 8]     = v0;
    *(float4*)&colbuf[rib][cg * 8 + 4] = v1;

    __shared__ double red[256];
    red[tid] = (double)p;
    __syncthreads();
    for (int off = 128; off > 0; off >>= 1) {
        if (tid < off) red[tid] += red[tid + off];
        __syncthreads();
    }
    if (tid == 0) Tpart[blockIdx.x] = red[0];

    if (tid < 64) {
        float cs = 0.f;
#pragma unroll
        for (int r2 = 0; r2 < 32; ++r2) cs += colbuf[r2][tid];
        Spart[blockIdx.x * 64 + tid] = cs;
    }
}

// ---- k_bw2: finalize bandwidth (cq = log2e/(4 bw)) + nsqq[i] = -sq[i]*cq ----
__global__ __launch_bounds__(256) void k_bw2(const double* __restrict__ Tpart, int ntp,
                                             const float* __restrict__ Spart, int nsp,
                                             int N, const float* __restrict__ sq,
                                             float* __restrict__ nsqq, float* __restrict__ cq_p) {
    int t = threadIdx.x;
    // column partial: 4 thread-quarters per column
    float colp = 0.f;
    for (int b = (t >> 6); b < nsp; b += 4) colp += Spart[b * 64 + (t & 63)];
    __shared__ float cred[256];
    cred[t] = colp;
    double Tp = 0.0;
    for (int b = t; b < ntp; b += 256) Tp += Tpart[b];
    __shared__ double red[256];
    red[t] = Tp;
    __syncthreads();
    for (int off = 128; off > 0; off >>= 1) {
        if (t < off) red[t] += red[t + off];
        __syncthreads();
    }
    double T = red[0];
    __shared__ double red2[64];
    if (t < 64) {
        float Sk = cred[t] + cred[t + 64] + cred[t + 128] + cred[t + 192];
        red2[t] = (double)Sk * (double)Sk;
    }
    __shared__ float cqs;
    __syncthreads();
    if (t == 0) {
        double S2 = 0.0;
        for (int i = 0; i < 64; ++i) S2 += red2[i];
        double sumd2 = 2.0 * (double)N * T - 2.0 * S2;
        double bw = sumd2 / ((double)N * (double)N - (double)N);
        float cq = (float)(1.4426950408889634 / (4.0 * bw));
        cq_p[0] = cq;
        cqs = cq;
    }
    __syncthreads();
    float cq = cqs;
    for (int it = 0; it < N / 256; ++it) {
        int i = it * 256 + t;
        nsqq[i] = -sq[i] * cq;
    }
}

// ---- k_mmd: lower-triangle, 128-row strip x 512-col chunk per block ----
// Row group g (4 rows of 128): rows 4g..4g+3, each with g+1 chunks of 512 cols.
// prefix(g) = 2g(g+1). Diagonal 128x128 tile (last of each row) weighted 1, rest 2.
// u4 = (2*dot - sqi - sqj)*log2e/(4bw) clamped <=0; Eq=2^u4; K = Eq+Eq^2+Eq^4+Eq^8+Eq^16.
__global__ __launch_bounds__(256, 4) void k_mmd(const _Float16* __restrict__ zh,
                                                const float* __restrict__ nsqq,
                                                const float* __restrict__ cq_p,
                                                int nb, double* __restrict__ partial) {
    int bid = (nb - 1) - (int)blockIdx.x;       // longest blocks first
    int g = (int)((sqrtf(1.0f + 2.0f * (float)bid) - 1.0f) * 0.5f);
    while (2 * (g + 1) * (g + 2) <= bid) ++g;
    while (2 * g * (g + 1) > bid) --g;
    int r = bid - 2 * g * (g + 1);
    int gp1 = g + 1;
    int rig = r / gp1;
    int jc  = r - rig * gp1;
    int ib  = 4 * g + rig;

    int jstart = jc * 512;
    int jend   = (ib + 1) * 128;
    if (jend > jstart + 512) jend = jstart + 512;
    int njt = (jend - jstart) >> 4;
    int diag_j = ib * 128;

    int lane = threadIdx.x & 63;
    int wid  = threadIdx.x >> 6;
    int i0 = ib * 128 + wid * 32;

    float c2q = 2.0f * cq_p[0];

    int lrow = lane & 15;
    int kb = (lane >> 4) * 8;

    const _Float16* ar0 = zh + (size_t)(i0 + lrow) * D + kb;
    half8 a00 = *(const half8*)(ar0);
    half8 a01 = *(const half8*)(ar0 + 32);
    half8 a10 = *(const half8*)(ar0 + 16 * D);
    half8 a11 = *(const half8*)(ar0 + 16 * D + 32);

    int irh = (lane >> 4) * 4;
    float nai0[4], nai1[4];
#pragma unroll
    for (int rr = 0; rr < 4; ++rr) {
        nai0[rr] = nsqq[i0 + irh + rr];
        nai1[rr] = nsqq[i0 + 16 + irh + rr];
    }

    const _Float16* bptr = zh + (size_t)(jstart + lrow) * D + kb;
    const float* nsqj = nsqq + jstart + lrow;

    float acc = 0.f;
    int jcur = jstart;
#pragma unroll 2
    for (int jt = 0; jt < njt; ++jt) {
        half8 b0 = *(const half8*)(bptr);
        half8 b1 = *(const half8*)(bptr + 32);
        float nbj = nsqj[0];
        floatx4 d0 = {0.f, 0.f, 0.f, 0.f};
        floatx4 d1 = {0.f, 0.f, 0.f, 0.f};
        d0 = __builtin_amdgcn_mfma_f32_16x16x32_f16(a00, b0, d0, 0, 0, 0);
        d0 = __builtin_amdgcn_mfma_f32_16x16x32_f16(a01, b1, d0, 0, 0, 0);
        d1 = __builtin_amdgcn_mfma_f32_16x16x32_f16(a10, b0, d1, 0, 0, 0);
        d1 = __builtin_amdgcn_mfma_f32_16x16x32_f16(a11, b1, d1, 0, 0, 0);

        float part = 0.f;
#pragma unroll
        for (int rr = 0; rr < 4; ++rr) {
            float u0 = fminf(fmaf(d0[rr], c2q, nai0[rr] + nbj), 0.f);
            float u1 = fminf(fmaf(d1[rr], c2q, nai1[rr] + nbj), 0.f);
            float q0 = __builtin_amdgcn_exp2f(u0);
            float q1 = __builtin_amdgcn_exp2f(u1);
            float m01 = q0 * q0,   m11 = q1 * q1;     // Eq^2
            float m02 = m01 * m01, m12 = m11 * m11;   // Eq^4
            float m03 = m02 * m02, m13 = m12 * m12;   // Eq^8
            float s0 = (q0 + m01) + (m02 + m03);
            float s1 = (q1 + m11) + (m12 + m13);
            part += fmaf(m03, m03, s0) + fmaf(m13, m13, s1);  // + Eq^16
        }
        float wf = (jcur >= diag_j) ? 1.0f : 2.0f;
        acc = fmaf(part, wf, acc);

        jcur += 16;
        bptr += (size_t)16 * D;
        nsqj += 16;
    }

    // wave reduce (f64), then tiny LDS combine across the 4 waves
    double wacc = (double)acc;
    wacc += __shfl_xor(wacc, 1);
    wacc += __shfl_xor(wacc, 2);
    wacc += __shfl_xor(wacc, 4);
    wacc += __shfl_xor(wacc, 8);
    wacc += __shfl_xor(wacc, 16);
    wacc += __shfl_xor(wacc, 32);
    __shared__ double redw[4];
    if (lane == 0) redw[wid] = wacc;
    __syncthreads();
    if (threadIdx.x == 0) partial[bid] = (redw[0] + redw[1]) + (redw[2] + redw[3]);
}

// ---- k_final: classify weighted partials into XX/XY/YY, finalize ----
__global__ __launch_bounds__(256) void k_final(const double* __restrict__ partial, int nb,
                                               int nxTile, int nxChunk,
                                               int nx, int ny, float* __restrict__ out) {
    int t = threadIdx.x;
    double sXX = 0.0, sXY = 0.0, sYY = 0.0;
    for (int p = t; p < nb; p += 256) {
        int g = (int)((sqrtf(1.0f + 2.0f * (float)p) - 1.0f) * 0.5f);
        while (2 * (g + 1) * (g + 2) <= p) ++g;
        while (2 * g * (g + 1) > p) --g;
        int r = p - 2 * g * (g + 1);
        int gp1 = g + 1;
        int rig = r / gp1;
        int jc  = r - rig * gp1;
        int ib  = 4 * g + rig;
        double v = partial[p];
        bool iX = ib < nxTile;
        bool jX = jc < nxChunk;
        if (iX && jX) sXX += v;
        else if (iX != jX) sXY += v;
        else sYY += v;
    }
    __shared__ double r0[256], r1[256], r2[256];
    r0[t] = sXX; r1[t] = sXY; r2[t] = sYY;
    __syncthreads();
    for (int off = 128; off > 0; off >>= 1) {
        if (t < off) {
            r0[t] += r0[t + off];
            r1[t] += r1[t + off];
            r2[t] += r2[t + off];
        }
        __syncthreads();
    }
    if (t == 0) {
        double XX = r0[0] / ((double)nx * (double)nx);
        double XY = r1[0] / (2.0 * (double)nx * (double)ny);  // weighted mixed = both halves
        double YY = r2[0] / ((double)ny * (double)ny);
        out[0] = (float)(XX - 2.0 * XY + YY);
    }
}

extern "C" void kernel_launch(void* const* d_in, const int* in_sizes, int n_in,
                              void* d_out, int out_size, void* d_ws, size_t ws_size,
                              hipStream_t stream) {
    const float* x = (const float*)d_in[0];
    const float* y = (const float*)d_in[1];
    float* out = (float*)d_out;

    int nx = in_sizes[0] / D;     // 8192
    int ny = in_sizes[1] / D;     // 8192
    int N  = nx + ny;             // 16384

    int pre_blocks = (N * D / 8) / 256;    // 512 (32 rows per block)
    int nT = N / 128;                      // 128 i-tiles
    int ngr = nT / 4;                      // 32 row groups
    int nb = 2 * ngr * (ngr + 1);          // 2112 triangle chunk-blocks
    int nxTile = nx / 128;                 // 64
    int nxChunk = nx / 512;                // 16

    // workspace layout (every buffer fully written before read, every launch)
    char* w = (char*)d_ws;
    double* Tpart   = (double*)(w + 0);        // 512*8    = 4096          -> 4096
    double* partial = (double*)(w + 4096);     // 2112*8   = 16896         -> 20992
    float*  Spart   = (float*) (w + 20992);    // 512*64*4 = 131072        -> 152064
    float*  sq      = (float*) (w + 152064);   // N*4      = 65536         -> 217600
    float*  nsqq    = (float*) (w + 217600);   // N*4      = 65536         -> 283136
    float*  cq      = (float*) (w + 283136);   // 64 B pad                 -> 283200
    _Float16* zh    = (_Float16*)(w + 283200); // N*64*2   = 2 MiB

    k_pre   <<<pre_blocks, 256, 0, stream>>>(x, y, nx, zh, sq, Tpart, Spart);
    k_bw2   <<<1, 256, 0, stream>>>(Tpart, pre_blocks, Spart, pre_blocks, N, sq, nsqq, cq);
    k_mmd   <<<nb, 256, 0, stream>>>(zh, nsqq, cq, nb, partial);
    k_final <<<1, 256, 0, stream>>>(partial, nb, nxTile, nxChunk, nx, ny, out);
}

// Round 7
// 148.667 us; speedup vs baseline: 5.3889x; 1.2406x over previous
//
#include <hip/hip_runtime.h>
#include <hip/hip_bf16.h>

#define D 64

typedef __attribute__((ext_vector_type(8))) _Float16 half8;
typedef __attribute__((ext_vector_type(4))) float floatx4;

// ---- k_pre: fp16 convert + per-row sq + block partial sum(z^2) + block column sums ----
__global__ __launch_bounds__(256) void k_pre(const float* __restrict__ x, const float* __restrict__ y,
                                             int nx, _Float16* __restrict__ zh,
                                             float* __restrict__ sq, double* __restrict__ Tpart,
                                             float* __restrict__ Spart) {
    int tid = threadIdx.x;
    int lane = tid & 63, wid = tid >> 6;
    int t = blockIdx.x * 256 + tid;             // 8 elements per thread; block = 32 rows
    size_t e = (size_t)t * 8;
    int row = (int)(e >> 6);
    const float* src = (row < nx) ? (x + e) : (y + (e - (size_t)nx * D));
    float4 v0 = ((const float4*)src)[0];
    float4 v1 = ((const float4*)src)[1];
    half8 h;
    h[0]=(_Float16)v0.x; h[1]=(_Float16)v0.y; h[2]=(_Float16)v0.z; h[3]=(_Float16)v0.w;
    h[4]=(_Float16)v1.x; h[5]=(_Float16)v1.y; h[6]=(_Float16)v1.z; h[7]=(_Float16)v1.w;
    *(half8*)(zh + e) = h;
    float p = v0.x*v0.x + v0.y*v0.y + v0.z*v0.z + v0.w*v0.w
            + v1.x*v1.x + v1.y*v1.y + v1.z*v1.z + v1.w*v1.w;
    // row-sum across the 8 consecutive lanes sharing this row
    float s = p;
    s += __shfl_xor(s, 1);
    s += __shfl_xor(s, 2);
    s += __shfl_xor(s, 4);
    if ((tid & 7) == 0) sq[row] = s;

    // stage this thread's 8 column values for the block column-sum
    __shared__ float colbuf[32][64];
    int rib = tid >> 3, cg = tid & 7;
    *(float4*)&colbuf[rib][cg * 8]     = v0;
    *(float4*)&colbuf[rib][cg * 8 + 4] = v1;

    // block sum(z^2): f64 wave shfl-reduce + 4-slot LDS combine
    double dp = (double)p;
    dp += __shfl_xor(dp, 1);
    dp += __shfl_xor(dp, 2);
    dp += __shfl_xor(dp, 4);
    dp += __shfl_xor(dp, 8);
    dp += __shfl_xor(dp, 16);
    dp += __shfl_xor(dp, 32);
    __shared__ double redw[4];
    if (lane == 0) redw[wid] = dp;
    __syncthreads();
    if (tid == 0) Tpart[blockIdx.x] = (redw[0] + redw[1]) + (redw[2] + redw[3]);

    if (tid < 64) {
        float cs = 0.f;
#pragma unroll
        for (int r2 = 0; r2 < 32; ++r2) cs += colbuf[r2][tid];
        Spart[blockIdx.x * 64 + tid] = cs;
    }
}

// ---- k_bw: reduce Tpart/Spart -> cq = log2e/(4*bw) ----
__global__ __launch_bounds__(256) void k_bw(const double* __restrict__ Tpart, int ntp,
                                            const float* __restrict__ Spart, int nsp,
                                            int N, float* __restrict__ cq_p) {
    int t = threadIdx.x;
    double Tp = 0.0;
    for (int b = t; b < ntp; b += 256) Tp += Tpart[b];

    // column sums: thread t handles column t&63 over quarter t>>6 of blocks,
    // with 4 independent accumulator chains to keep loads pipelined.
    int q = t >> 6, col = t & 63;
    int bpq = nsp >> 2;
    const float* sp = Spart + (size_t)(q * bpq) * 64 + col;
    float c0 = 0.f, c1 = 0.f, c2 = 0.f, c3 = 0.f;
    for (int b = 0; b < bpq; b += 4) {
        c0 += sp[(b + 0) * 64];
        c1 += sp[(b + 1) * 64];
        c2 += sp[(b + 2) * 64];
        c3 += sp[(b + 3) * 64];
    }
    __shared__ float cred[256];
    cred[t] = (c0 + c1) + (c2 + c3);

    __shared__ double red[256];
    red[t] = Tp;
    __syncthreads();
    for (int off = 128; off > 0; off >>= 1) {
        if (t < off) red[t] += red[t + off];
        __syncthreads();
    }
    double T = red[0];
    __shared__ double red2[64];
    if (t < 64) {
        float Sk = cred[t] + cred[t + 64] + cred[t + 128] + cred[t + 192];
        red2[t] = (double)Sk * (double)Sk;
    }
    __syncthreads();
    if (t == 0) {
        double S2 = 0.0;
        for (int i = 0; i < 64; ++i) S2 += red2[i];
        double sumd2 = 2.0 * (double)N * T - 2.0 * S2;
        double bw = sumd2 / ((double)N * (double)N - (double)N);
        cq_p[0] = (float)(1.4426950408889634 / (4.0 * bw));
    }
}

// ---- k_mmd: lower-triangle, 128-row strip x 512-col chunk, 2-deep SW pipeline ----
// u4 = (2*dot - sqi - sqj)*log2e/(4bw) clamped <=0; Eq=2^u4; K = Eq+Eq^2+Eq^4+Eq^8+Eq^16.
__global__ __launch_bounds__(256, 4) void k_mmd(const _Float16* __restrict__ zh,
                                                const float* __restrict__ sq,
                                                const float* __restrict__ cq_p,
                                                int nb, double* __restrict__ partial) {
    int bid = (nb - 1) - (int)blockIdx.x;       // longest blocks first
    int g = (int)((sqrtf(1.0f + 2.0f * (float)bid) - 1.0f) * 0.5f);
    while (2 * (g + 1) * (g + 2) <= bid) ++g;
    while (2 * g * (g + 1) > bid) --g;
    int r = bid - 2 * g * (g + 1);
    int gp1 = g + 1;
    int rig = r / gp1;
    int jc  = r - rig * gp1;
    int ib  = 4 * g + rig;

    int jstart = jc * 512;
    int jend   = (ib + 1) * 128;
    if (jend > jstart + 512) jend = jstart + 512;
    int njt = (jend - jstart) >> 4;             // in {8,16,24,32}, always even
    int diag_j = ib * 128;

    int lane = threadIdx.x & 63;
    int wid  = threadIdx.x >> 6;
    int i0 = ib * 128 + wid * 32;

    float cq  = cq_p[0];
    float c2q = 2.0f * cq;

    int lrow = lane & 15;
    int kb = (lane >> 4) * 8;

    const _Float16* ar0 = zh + (size_t)(i0 + lrow) * D + kb;
    half8 a00 = *(const half8*)(ar0);
    half8 a01 = *(const half8*)(ar0 + 32);
    half8 a10 = *(const half8*)(ar0 + 16 * D);
    half8 a11 = *(const half8*)(ar0 + 16 * D + 32);

    int irh = (lane >> 4) * 4;
    float nai0[4], nai1[4];
#pragma unroll
    for (int rr = 0; rr < 4; ++rr) {
        nai0[rr] = -sq[i0 + irh + rr] * cq;
        nai1[rr] = -sq[i0 + 16 + irh + rr] * cq;
    }

    const _Float16* bptr = zh + (size_t)(jstart + lrow) * D + kb;
    const float* sqjp = sq + jstart + lrow;

    float acc = 0.f;

    auto compute = [&](half8 b0, half8 b1, float sqj, float wf) {
        float nbj = -sqj * cq;
        floatx4 d0 = {0.f, 0.f, 0.f, 0.f};
        floatx4 d1 = {0.f, 0.f, 0.f, 0.f};
        d0 = __builtin_amdgcn_mfma_f32_16x16x32_f16(a00, b0, d0, 0, 0, 0);
        d0 = __builtin_amdgcn_mfma_f32_16x16x32_f16(a01, b1, d0, 0, 0, 0);
        d1 = __builtin_amdgcn_mfma_f32_16x16x32_f16(a10, b0, d1, 0, 0, 0);
        d1 = __builtin_amdgcn_mfma_f32_16x16x32_f16(a11, b1, d1, 0, 0, 0);
        float part = 0.f;
#pragma unroll
        for (int rr = 0; rr < 4; ++rr) {
            float u0 = fminf(fmaf(d0[rr], c2q, nai0[rr] + nbj), 0.f);
            float u1 = fminf(fmaf(d1[rr], c2q, nai1[rr] + nbj), 0.f);
            float q0 = __builtin_amdgcn_exp2f(u0);
            float q1 = __builtin_amdgcn_exp2f(u1);
            float m01 = q0 * q0,   m11 = q1 * q1;     // Eq^2
            float m02 = m01 * m01, m12 = m11 * m11;   // Eq^4
            float m03 = m02 * m02, m13 = m12 * m12;   // Eq^8
            float s0 = (q0 + m01) + (m02 + m03);
            float s1 = (q1 + m11) + (m12 + m13);
            part += fmaf(m03, m03, s0) + fmaf(m13, m13, s1);  // + Eq^16
        }
        acc = fmaf(part, wf, acc);
    };

    // ---- 2-deep software pipeline over even njt >= 8 ----
    half8 b0A = *(const half8*)(bptr);
    half8 b1A = *(const half8*)(bptr + 32);
    float sA  = sqjp[0];
    half8 b0B = *(const half8*)(bptr + 16 * D);
    half8 b1B = *(const half8*)(bptr + 16 * D + 32);
    float sB  = sqjp[16];

    const _Float16* bp2 = bptr + 32 * D;
    const float* sp2 = sqjp + 32;
    int jcur = jstart;

    for (int jt = 0; jt + 2 < njt; jt += 2) {
        // prefetch jt+2 / jt+3, then compute jt / jt+1
        half8 p0 = *(const half8*)(bp2);
        half8 p1 = *(const half8*)(bp2 + 32);
        float ps = sp2[0];
        float wA = (jcur >= diag_j) ? 1.0f : 2.0f;
        compute(b0A, b1A, sA, wA);
        b0A = p0; b1A = p1; sA = ps;

        p0 = *(const half8*)(bp2 + 16 * D);
        p1 = *(const half8*)(bp2 + 16 * D + 32);
        ps = sp2[16];
        float wB = (jcur + 16 >= diag_j) ? 1.0f : 2.0f;
        compute(b0B, b1B, sB, wB);
        b0B = p0; b1B = p1; sB = ps;

        bp2 += 32 * D;
        sp2 += 32;
        jcur += 32;
    }
    {
        float wA = (jcur >= diag_j) ? 1.0f : 2.0f;
        compute(b0A, b1A, sA, wA);
        float wB = (jcur + 16 >= diag_j) ? 1.0f : 2.0f;
        compute(b0B, b1B, sB, wB);
    }

    // wave reduce (f64), then tiny LDS combine across the 4 waves
    double wacc = (double)acc;
    wacc += __shfl_xor(wacc, 1);
    wacc += __shfl_xor(wacc, 2);
    wacc += __shfl_xor(wacc, 4);
    wacc += __shfl_xor(wacc, 8);
    wacc += __shfl_xor(wacc, 16);
    wacc += __shfl_xor(wacc, 32);
    __shared__ double redw[4];
    if (lane == 0) redw[wid] = wacc;
    __syncthreads();
    if (threadIdx.x == 0) partial[bid] = (redw[0] + redw[1]) + (redw[2] + redw[3]);
}

// ---- k_final: classify weighted partials into XX/XY/YY, finalize ----
__global__ __launch_bounds__(256) void k_final(const double* __restrict__ partial, int nb,
                                               int nxTile, int nxChunk,
                                               int nx, int ny, float* __restrict__ out) {
    int t = threadIdx.x;
    double sXX = 0.0, sXY = 0.0, sYY = 0.0;
    for (int p = t; p < nb; p += 256) {
        int g = (int)((sqrtf(1.0f + 2.0f * (float)p) - 1.0f) * 0.5f);
        while (2 * (g + 1) * (g + 2) <= p) ++g;
        while (2 * g * (g + 1) > p) --g;
        int r = p - 2 * g * (g + 1);
        int gp1 = g + 1;
        int rig = r / gp1;
        int jc  = r - rig * gp1;
        int ib  = 4 * g + rig;
        double v = partial[p];
        bool iX = ib < nxTile;
        bool jX = jc < nxChunk;
        if (iX && jX) sXX += v;
        else if (iX != jX) sXY += v;
        else sYY += v;
    }
    __shared__ double r0[256], r1[256], r2[256];
    r0[t] = sXX; r1[t] = sXY; r2[t] = sYY;
    __syncthreads();
    for (int off = 128; off > 0; off >>= 1) {
        if (t < off) {
            r0[t] += r0[t + off];
            r1[t] += r1[t + off];
            r2[t] += r2[t + off];
        }
        __syncthreads();
    }
    if (t == 0) {
        double XX = r0[0] / ((double)nx * (double)nx);
        double XY = r1[0] / (2.0 * (double)nx * (double)ny);  // weighted mixed = both halves
        double YY = r2[0] / ((double)ny * (double)ny);
        out[0] = (float)(XX - 2.0 * XY + YY);
    }
}

extern "C" void kernel_launch(void* const* d_in, const int* in_sizes, int n_in,
                              void* d_out, int out_size, void* d_ws, size_t ws_size,
                              hipStream_t stream) {
    const float* x = (const float*)d_in[0];
    const float* y = (const float*)d_in[1];
    float* out = (float*)d_out;

    int nx = in_sizes[0] / D;     // 8192
    int ny = in_sizes[1] / D;     // 8192
    int N  = nx + ny;             // 16384

    int pre_blocks = (N * D / 8) / 256;    // 512 (32 rows per block)
    int nT = N / 128;                      // 128 i-tiles
    int ngr = nT / 4;                      // 32 row groups
    int nb = 2 * ngr * (ngr + 1);          // 2112 triangle chunk-blocks
    int nxTile = nx / 128;                 // 64
    int nxChunk = nx / 512;                // 16

    // workspace layout (every buffer fully written before read, every launch)
    char* w = (char*)d_ws;
    double* Tpart   = (double*)(w + 0);        // 512*8    = 4096          -> 4096
    double* partial = (double*)(w + 4096);     // 2112*8   = 16896         -> 20992
    float*  Spart   = (float*) (w + 20992);    // 512*64*4 = 131072        -> 152064
    float*  sq      = (float*) (w + 152064);   // N*4      = 65536         -> 217600
    float*  cq      = (float*) (w + 217600);   // 64 B pad                 -> 217664
    _Float16* zh    = (_Float16*)(w + 217664); // N*64*2   = 2 MiB

    k_pre   <<<pre_blocks, 256, 0, stream>>>(x, y, nx, zh, sq, Tpart, Spart);
    k_bw    <<<1, 256, 0, stream>>>(Tpart, pre_blocks, Spart, pre_blocks, N, cq);
    k_mmd   <<<nb, 256, 0, stream>>>(zh, sq, cq, nb, partial);
    k_final <<<1, 256, 0, stream>>>(partial, nb, nxTile, nxChunk, nx, ny, out);
}